// Round 1
// baseline (7553.854 us; speedup 1.0000x reference)
//
#include <hip/hip_runtime.h>
#include <hip/hip_bf16.h>
#include <stdint.h>

// LSTM: T=512, B=64, D=1024, H=1024, gates order i,f,g,o
#define T_STEPS 512
#define BATCH   64
#define DIM     1024
#define HID     1024
#define NG      4096                 // 4*HID
#define MROWS   (T_STEPS * BATCH)    // 32768

typedef __bf16 bf16;
typedef __bf16 bf16x4 __attribute__((ext_vector_type(4)));
typedef __bf16 bf16x8 __attribute__((ext_vector_type(8)));
typedef float  f32x4  __attribute__((ext_vector_type(4)));

__device__ __forceinline__ void g2lds16(const void* g, void* l) {
    __builtin_amdgcn_global_load_lds(
        (const __attribute__((address_space(1))) void*)g,
        (__attribute__((address_space(3))) void*)l, 16, 0, 0);
}

__device__ __forceinline__ float fsigmoid(float x) {
    return 1.0f / (1.0f + __expf(-x));   // safe at +-inf
}
__device__ __forceinline__ float ftanh_(float x) {
    return 1.0f - 2.0f / (__expf(2.0f * x) + 1.0f);   // safe at +-inf
}

// ---------------------------------------------------------------------------
// prep: fp32->bf16 conversions, W_ih column-permute (n' = (n&1023)*4 + (n>>10)),
// bias sum (permuted), zero h0 buffer and barrier flags.
// ---------------------------------------------------------------------------
__global__ __launch_bounds__(256) void prep_kernel(
    const float* __restrict__ x,   const float* __restrict__ wih,
    const float* __restrict__ whh, const float* __restrict__ bih,
    const float* __restrict__ bhh,
    bf16* __restrict__ xb, bf16* __restrict__ wihp, bf16* __restrict__ whhb,
    float* __restrict__ bsump, bf16* __restrict__ hbuf, unsigned* __restrict__ flags)
{
    const int nt  = gridDim.x * blockDim.x;
    const int gid = blockIdx.x * blockDim.x + threadIdx.x;

    for (int i = gid; i < MROWS * DIM / 4; i += nt) {
        f32x4 v = *(const f32x4*)(x + (size_t)i * 4);
        bf16x4 o = {(bf16)v[0], (bf16)v[1], (bf16)v[2], (bf16)v[3]};
        *(bf16x4*)(xb + (size_t)i * 4) = o;
    }
    for (int i = gid; i < NG * (DIM / 4); i += nt) {
        const int n = i >> 8, c4 = (i & 255) * 4;
        f32x4 v = *(const f32x4*)(wih + (size_t)n * DIM + c4);
        bf16x4 o = {(bf16)v[0], (bf16)v[1], (bf16)v[2], (bf16)v[3]};
        const int np = ((n & 1023) << 2) | (n >> 10);
        *(bf16x4*)(wihp + (size_t)np * DIM + c4) = o;
    }
    for (int i = gid; i < NG * (HID / 4); i += nt) {
        f32x4 v = *(const f32x4*)(whh + (size_t)i * 4);
        bf16x4 o = {(bf16)v[0], (bf16)v[1], (bf16)v[2], (bf16)v[3]};
        *(bf16x4*)(whhb + (size_t)i * 4) = o;
    }
    for (int i = gid; i < NG; i += nt)
        bsump[((i & 1023) << 2) | (i >> 10)] = bih[i] + bhh[i];
    for (int i = gid; i < BATCH * HID / 4; i += nt) {
        bf16x4 z = {(bf16)0.f, (bf16)0.f, (bf16)0.f, (bf16)0.f};
        *(bf16x4*)(hbuf + (size_t)i * 4) = z;   // h[buf 0] = 0
    }
    for (int i = gid; i < 256 * 16; i += nt)
        flags[i] = 0u;
}

// ---------------------------------------------------------------------------
// xg GEMM: C[32768,4096] = xb[32768,1024] @ wihp^T + bsump, bf16 out.
// m97-style: 128x128 tile, BK=32, 4 waves (2x2), global_load_lds width 16.
// ---------------------------------------------------------------------------
__global__ __launch_bounds__(256) void gemm_kernel(
    const bf16* __restrict__ A, const bf16* __restrict__ B,
    const float* __restrict__ bsum, bf16* __restrict__ xgp)
{
    __shared__ char lds[16384];
    char* As = lds;
    char* Bs = lds + 8192;

    const int tid  = threadIdx.x;
    const int lane = tid & 63;
    const int wv   = tid >> 6;
    const int wr   = wv >> 1, wc = wv & 1;
    const int bx   = blockIdx.x & 31;   // N tile
    const int by   = blockIdx.x >> 5;   // M tile
    const int m0   = by * 128, n0 = bx * 128;

    f32x4 acc[4][4] = {};

    const int r4 = tid >> 2;            // staging row within 64-row group
    const int c8 = (tid & 3) * 8;       // staging k-elem offset
    const size_t arow0 = (size_t)(m0 +      r4) * DIM + c8;
    const size_t arow1 = (size_t)(m0 + 64 + r4) * DIM + c8;
    const size_t brow0 = (size_t)(n0 +      r4) * DIM + c8;
    const size_t brow1 = (size_t)(n0 + 64 + r4) * DIM + c8;
    const int ldsoff = tid * 16;

    for (int k0 = 0; k0 < DIM; k0 += 32) {
        g2lds16(A + arow0 + k0, As + ldsoff);
        g2lds16(A + arow1 + k0, As + 4096 + ldsoff);
        g2lds16(B + brow0 + k0, Bs + ldsoff);
        g2lds16(B + brow1 + k0, Bs + 4096 + ldsoff);
        __syncthreads();   // drains vmcnt -> tiles resident

        bf16x8 af[4], bfr[4];
        #pragma unroll
        for (int i = 0; i < 4; ++i) {
            af[i]  = *(const bf16x8*)(As + (wr*64 + i*16 + (lane & 15))*64 + (lane >> 4)*16);
            bfr[i] = *(const bf16x8*)(Bs + (wc*64 + i*16 + (lane & 15))*64 + (lane >> 4)*16);
        }
        #pragma unroll
        for (int i = 0; i < 4; ++i)
            #pragma unroll
            for (int j = 0; j < 4; ++j)
                acc[i][j] = __builtin_amdgcn_mfma_f32_16x16x32_bf16(
                    af[i], bfr[j], acc[i][j], 0, 0, 0);
        __syncthreads();   // all reads done before next-stage overwrite
    }

    // epilogue: C/D layout col=lane&15, row=(lane>>4)*4+r
    #pragma unroll
    for (int j = 0; j < 4; ++j) {
        const int nn = n0 + wc*64 + j*16 + (lane & 15);
        const float bias = bsum[nn];
        #pragma unroll
        for (int i = 0; i < 4; ++i) {
            #pragma unroll
            for (int r = 0; r < 4; ++r) {
                const int mm = m0 + wr*64 + i*16 + ((lane >> 4) << 2) + r;
                xgp[(size_t)mm * NG + nn] = (bf16)(acc[i][j][r] + bias);
            }
        }
    }
}

// ---------------------------------------------------------------------------
// Persistent recurrent kernel: 256 WGs x 256 threads, WG w owns hidden units
// [4w,4w+4) (16 gate rows of W_hh in LDS). c in registers. h double-buffered
// bf16 in global; one fence-based grid barrier per step.
// ---------------------------------------------------------------------------
__global__ __launch_bounds__(256) void lstm_kernel(
    const bf16* __restrict__ xgp, const bf16* __restrict__ whhb,
    bf16* __restrict__ hbuf, unsigned* __restrict__ flags,
    float* __restrict__ out)
{
    const int tid  = threadIdx.x;
    const int wg   = blockIdx.x;
    const int lane = tid & 63;
    const int wv   = tid >> 6;
    const int frow = lane & 15;   // MFMA fragment row / output col
    const int fk   = lane >> 4;   // k-group
    const int bb   = tid >> 2;    // batch row for elementwise
    const int jj   = tid & 3;     // hidden unit within WG

    __shared__ short wlds[16 * 1032];   // 16 gate rows, pitch 2064B (2-way = free)
    __shared__ float gbuf[64][17];

    // load W_hh rows: lds row r <-> gate (r>>2), hidden col wg*4 + (r&3)
    for (int i = tid; i < 16 * 256; i += 256) {
        const int r = i >> 8, cc = i & 255;
        const int grow = ((r >> 2) << 10) + (wg << 2) + (r & 3);
        *(bf16x4*)&wlds[r * 1032 + cc * 4] =
            *(const bf16x4*)(whhb + (size_t)grow * HID + cc * 4);
    }
    float c = 0.f;
    __syncthreads();

    #pragma unroll 1
    for (int step = 0; step < T_STEPS; ++step) {
        const bf16* h = hbuf + (step & 1) * (BATCH * HID);

        // issue all 32 h-fragment loads first (hide LLC latency), then MFMA
        bf16x8 af[32];
        #pragma unroll
        for (int kk = 0; kk < 32; ++kk)
            af[kk] = *(const bf16x8*)(h + (16*wv + frow) * HID + kk * 32 + fk * 8);

        f32x4 acc0 = {0.f, 0.f, 0.f, 0.f}, acc1 = {0.f, 0.f, 0.f, 0.f};
        #pragma unroll
        for (int kk = 0; kk < 32; kk += 2) {
            acc0 = __builtin_amdgcn_mfma_f32_16x16x32_bf16(
                af[kk],   *(const bf16x8*)&wlds[frow*1032 + (kk    )*32 + fk*8], acc0, 0,0,0);
            acc1 = __builtin_amdgcn_mfma_f32_16x16x32_bf16(
                af[kk+1], *(const bf16x8*)&wlds[frow*1032 + (kk + 1)*32 + fk*8], acc1, 0,0,0);
        }
        acc0 = acc0 + acc1;

        // scatter gates to LDS; each wave reads back only rows it wrote
        #pragma unroll
        for (int r = 0; r < 4; ++r)
            gbuf[16*wv + fk*4 + r][frow] = acc0[r];

        // all 4 gates of this (b, hidden) in one 8B load (permuted xg layout)
        bf16x4 xv = *(const bf16x4*)(xgp + ((size_t)step * BATCH + bb) * NG
                                          + (((wg << 2) + jj) << 2));
        const float P0 = gbuf[bb][0*4 + jj] + (float)xv[0];
        const float P1 = gbuf[bb][1*4 + jj] + (float)xv[1];
        const float P2 = gbuf[bb][2*4 + jj] + (float)xv[2];
        const float P3 = gbuf[bb][3*4 + jj] + (float)xv[3];
        const float ig = fsigmoid(P0);
        const float fg = fsigmoid(P1);
        const float gg = ftanh_(P2);
        const float og = fsigmoid(P3);
        c = fg * c + ig * gg;
        const float hv = og * ftanh_(c);

        out[((size_t)step * BATCH + bb) * HID + (wg << 2) + jj] = hv;
        hbuf[(1 - (step & 1)) * (BATCH * HID) + bb * HID + (wg << 2) + jj] = (bf16)hv;

        // ---- grid barrier (release/acquire at agent scope) ----
        __syncthreads();   // drains vmcnt: all WG stores at L2
        if (tid == 0) {
            __builtin_amdgcn_fence(__ATOMIC_RELEASE, "agent");   // wbl2 -> LLC
            __hip_atomic_store(&flags[wg * 16], (unsigned)(step + 1),
                               __ATOMIC_RELAXED, __HIP_MEMORY_SCOPE_AGENT);
        }
        while (__hip_atomic_load(&flags[tid * 16], __ATOMIC_RELAXED,
                                 __HIP_MEMORY_SCOPE_AGENT) < (unsigned)(step + 1))
            __builtin_amdgcn_s_sleep(1);
        __syncthreads();   // all 256 flags seen collectively
        if (tid == 0) __builtin_amdgcn_fence(__ATOMIC_ACQUIRE, "agent");  // inv L1/L2
        __syncthreads();
    }
}

// ---------------------------------------------------------------------------
extern "C" void kernel_launch(void* const* d_in, const int* in_sizes, int n_in,
                              void* d_out, int out_size, void* d_ws, size_t ws_size,
                              hipStream_t stream) {
    const float* x   = (const float*)d_in[0];   // [512,64,1024]
    const float* wih = (const float*)d_in[1];   // [4096,1024]
    const float* whh = (const float*)d_in[2];   // [4096,1024]
    const float* bih = (const float*)d_in[3];   // [4096]
    const float* bhh = (const float*)d_in[4];   // [4096]
    float* out = (float*)d_out;                 // [512,64,1024]

    char* ws = (char*)d_ws;
    size_t off = 0;
    bf16* xgp  = (bf16*)(ws + off); off += (size_t)MROWS * NG * 2;      // 256 MB
    bf16* xb   = (bf16*)(ws + off); off += (size_t)MROWS * DIM * 2;     //  64 MB
    bf16* wihp = (bf16*)(ws + off); off += (size_t)NG * DIM * 2;        //   8 MB
    bf16* whhb = (bf16*)(ws + off); off += (size_t)NG * HID * 2;        //   8 MB
    float* bsum = (float*)(ws + off); off += (size_t)NG * 4;            //  16 KB
    bf16* hbuf = (bf16*)(ws + off); off += (size_t)2 * BATCH * HID * 2; // 256 KB
    unsigned* flags = (unsigned*)(ws + off); off += 256 * 16 * 4;       //  16 KB
    (void)ws_size; (void)in_sizes; (void)n_in; (void)out_size;

    prep_kernel<<<2048, 256, 0, stream>>>(x, wih, whh, bih, bhh,
                                          xb, wihp, whhb, bsum, hbuf, flags);
    gemm_kernel<<<8192, 256, 0, stream>>>(xb, wihp, bsum, xgp);
    lstm_kernel<<<256, 256, 0, stream>>>(xgp, whhb, hbuf, flags, out);
}

// Round 2
// 2182.626 us; speedup vs baseline: 3.4609x; 3.4609x over previous
//
#include <hip/hip_runtime.h>
#include <hip/hip_bf16.h>
#include <stdint.h>

// LSTM: T=512, B=64, D=1024, H=1024, gates order i,f,g,o
#define T_STEPS 512
#define BATCH   64
#define DIM     1024
#define HID     1024
#define NG      4096                 // 4*HID
#define MROWS   (T_STEPS * BATCH)    // 32768

typedef __bf16 bf16;
typedef __bf16 bf16x4 __attribute__((ext_vector_type(4)));
typedef __bf16 bf16x8 __attribute__((ext_vector_type(8)));
typedef float  f32x4  __attribute__((ext_vector_type(4)));
typedef unsigned int u32;
typedef u32 u32x2 __attribute__((ext_vector_type(2)));
typedef u32 u32x4 __attribute__((ext_vector_type(4)));

__device__ __forceinline__ void g2lds16(const void* g, void* l) {
    __builtin_amdgcn_global_load_lds(
        (const __attribute__((address_space(1))) void*)g,
        (__attribute__((address_space(3))) void*)l, 16, 0, 0);
}

__device__ __forceinline__ float fsigmoid(float x) {
    return 1.0f / (1.0f + __expf(-x));   // safe at +-inf
}
__device__ __forceinline__ float ftanh_(float x) {
    return 1.0f - 2.0f / (__expf(2.0f * x) + 1.0f);   // safe at +-inf
}

// ---- LLC-coherent (bypass L1+L2) memory ops: no fences needed anywhere ----
__device__ __forceinline__ u32x4 load16_cc(const void* p) {
    u32x4 r;
    asm volatile("global_load_dwordx4 %0, %1, off sc0 sc1" : "=v"(r) : "v"(p) : "memory");
    return r;
}
__device__ __forceinline__ u32x2 load8_cached(const void* p) {
    u32x2 r;
    asm volatile("global_load_dwordx2 %0, %1, off" : "=v"(r) : "v"(p) : "memory");
    return r;
}
__device__ __forceinline__ void store2_cc(void* p, u32 v) {
    asm volatile("global_store_short %0, %1, off sc0 sc1" :: "v"(p), "v"(v) : "memory");
}
#define WAITVM(n) asm volatile("s_waitcnt vmcnt(" #n ")" ::: "memory")

// ---------------------------------------------------------------------------
// prep: fp32->bf16 conversions, W_ih column-permute (n' = (n&1023)*4 + (n>>10)),
// bias sum (permuted), zero h0 buffer and barrier flags.
// ---------------------------------------------------------------------------
__global__ __launch_bounds__(256) void prep_kernel(
    const float* __restrict__ x,   const float* __restrict__ wih,
    const float* __restrict__ bih, const float* __restrict__ bhh,
    bf16* __restrict__ xb, bf16* __restrict__ wihp,
    float* __restrict__ bsump, bf16* __restrict__ hbuf, u32* __restrict__ flags)
{
    const int nt  = gridDim.x * blockDim.x;
    const int gid = blockIdx.x * blockDim.x + threadIdx.x;

    for (int i = gid; i < MROWS * DIM / 4; i += nt) {
        f32x4 v = *(const f32x4*)(x + (size_t)i * 4);
        bf16x4 o = {(bf16)v[0], (bf16)v[1], (bf16)v[2], (bf16)v[3]};
        *(bf16x4*)(xb + (size_t)i * 4) = o;
    }
    for (int i = gid; i < NG * (DIM / 4); i += nt) {
        const int n = i >> 8, c4 = (i & 255) * 4;
        f32x4 v = *(const f32x4*)(wih + (size_t)n * DIM + c4);
        bf16x4 o = {(bf16)v[0], (bf16)v[1], (bf16)v[2], (bf16)v[3]};
        const int np = ((n & 1023) << 2) | (n >> 10);
        *(bf16x4*)(wihp + (size_t)np * DIM + c4) = o;
    }
    for (int i = gid; i < NG; i += nt)
        bsump[((i & 1023) << 2) | (i >> 10)] = bih[i] + bhh[i];
    for (int i = gid; i < BATCH * HID / 4; i += nt) {
        bf16x4 z = {(bf16)0.f, (bf16)0.f, (bf16)0.f, (bf16)0.f};
        *(bf16x4*)(hbuf + (size_t)i * 4) = z;   // h[buf 0] = 0
    }
    for (int i = gid; i < 256 * 16; i += nt)
        flags[i] = 0u;
}

// ---------------------------------------------------------------------------
// xg GEMM: C[32768,4096] = xb[32768,1024] @ wihp^T + bsump, bf16 out.
// 128x128 tile, BK=32, 4 waves (2x2), global_load_lds width 16.
// ---------------------------------------------------------------------------
__global__ __launch_bounds__(256) void gemm_kernel(
    const bf16* __restrict__ A, const bf16* __restrict__ B,
    const float* __restrict__ bsum, bf16* __restrict__ xgp)
{
    __shared__ char lds[16384];
    char* As = lds;
    char* Bs = lds + 8192;

    const int tid  = threadIdx.x;
    const int lane = tid & 63;
    const int wv   = tid >> 6;
    const int wr   = wv >> 1, wc = wv & 1;
    const int bx   = blockIdx.x & 31;   // N tile
    const int by   = blockIdx.x >> 5;   // M tile
    const int m0   = by * 128, n0 = bx * 128;

    f32x4 acc[4][4] = {};

    const int r4 = tid >> 2;
    const int c8 = (tid & 3) * 8;
    const size_t arow0 = (size_t)(m0 +      r4) * DIM + c8;
    const size_t arow1 = (size_t)(m0 + 64 + r4) * DIM + c8;
    const size_t brow0 = (size_t)(n0 +      r4) * DIM + c8;
    const size_t brow1 = (size_t)(n0 + 64 + r4) * DIM + c8;
    const int ldsoff = tid * 16;

    for (int k0 = 0; k0 < DIM; k0 += 32) {
        g2lds16(A + arow0 + k0, As + ldsoff);
        g2lds16(A + arow1 + k0, As + 4096 + ldsoff);
        g2lds16(B + brow0 + k0, Bs + ldsoff);
        g2lds16(B + brow1 + k0, Bs + 4096 + ldsoff);
        __syncthreads();

        bf16x8 af[4], bfr[4];
        #pragma unroll
        for (int i = 0; i < 4; ++i) {
            af[i]  = *(const bf16x8*)(As + (wr*64 + i*16 + (lane & 15))*64 + (lane >> 4)*16);
            bfr[i] = *(const bf16x8*)(Bs + (wc*64 + i*16 + (lane & 15))*64 + (lane >> 4)*16);
        }
        #pragma unroll
        for (int i = 0; i < 4; ++i)
            #pragma unroll
            for (int j = 0; j < 4; ++j)
                acc[i][j] = __builtin_amdgcn_mfma_f32_16x16x32_bf16(
                    af[i], bfr[j], acc[i][j], 0, 0, 0);
        __syncthreads();
    }

    #pragma unroll
    for (int j = 0; j < 4; ++j) {
        const int nn = n0 + wc*64 + j*16 + (lane & 15);
        const float bias = bsum[nn];
        #pragma unroll
        for (int i = 0; i < 4; ++i) {
            #pragma unroll
            for (int r = 0; r < 4; ++r) {
                const int mm = m0 + wr*64 + i*16 + ((lane >> 4) << 2) + r;
                xgp[(size_t)mm * NG + nn] = (bf16)(acc[i][j][r] + bias);
            }
        }
    }
}

// ---------------------------------------------------------------------------
// Persistent recurrent kernel, 2-D partition: wg = bg*64 + hg.
//   bg in [0,4): batch rows [16bg, 16bg+16)   (4 independent barrier groups)
//   hg in [0,64): hidden units [16hg, 16hg+16) -> 64 gate rows of W_hh in LDS
// Waves split K (256 each): each wave reads h[16 x 256] = 8 KB (no redundancy),
// computes 4 partial gate N-tiles, cross-wave reduce through LDS.
// All cross-WG traffic (h, flags) bypasses L1/L2 (sc0 sc1) -> coherent at LLC,
// so the grid barrier is just vmcnt(0) + flag store + poll. No cache fences.
// ---------------------------------------------------------------------------
__global__ __launch_bounds__(256, 1) void lstm_kernel(
    const bf16* __restrict__ xgp, const float* __restrict__ whh,
    bf16* __restrict__ hbuf, u32* __restrict__ flags, float* __restrict__ out)
{
    __shared__ short wlds[64 * 1024];     // 128 KB, XOR-swizzled rows
    __shared__ float gbuf[4][16][68];     // [wave][batch row][gate col], padded

    const int tid  = threadIdx.x;
    const int lane = tid & 63;
    const int wv   = tid >> 6;
    const int wg   = blockIdx.x;
    const int hg   = wg & 63;
    const int bg   = wg >> 6;

    // Fill W LDS: local row r = gatetype*16 + jj  <->  whh row gatetype*1024 + hg*16 + jj.
    // bf16, byte addr = r*2048 + k*2, XOR-swizzled with ((r&7)<<4).
    for (int i = 0; i < 64; ++i) {
        const int grow = (i >> 4) * 1024 + hg * 16 + (i & 15);
        f32x4 v = *(const f32x4*)(whh + (size_t)grow * HID + tid * 4);
        bf16x4 o = {(bf16)v[0], (bf16)v[1], (bf16)v[2], (bf16)v[3]};
        int byte = i * 2048 + tid * 8;
        byte ^= (i & 7) << 4;
        *(bf16x4*)((char*)wlds + byte) = o;
    }

    const int frow = lane & 15;          // MFMA A row (batch) / B col (gate)
    const int fk8  = (lane >> 4) * 8;    // k offset within K=32 tile
    const int b_el = tid >> 4;           // elementwise batch row (0..15)
    const int j_el = tid & 15;           // elementwise hidden unit (0..15)

    u32* myflag   = flags + ((bg * 64 + hg) << 4);
    u32* pollflag = flags + ((bg * 64 + (tid & 63)) << 4);

    float c = 0.f;
    __syncthreads();

    #pragma unroll 1
    for (int step = 0; step < T_STEPS; ++step) {
        // --- issue h fragment loads (LLC-coherent), then xg load (cached) ---
        const bf16* hb = hbuf + (step & 1) * (BATCH * HID)
                       + (size_t)(bg * 16 + frow) * HID + wv * 256 + fk8;
        u32x4 afr[8];
        #pragma unroll
        for (int kk = 0; kk < 8; ++kk)
            afr[kk] = load16_cc(hb + kk * 32);
        u32x2 xr = load8_cached(xgp + ((size_t)(step * BATCH + bg * 16 + b_el)) * NG
                                    + (16 * hg + j_el) * 4);
        WAITVM(2);                         // af done; xg may still be in flight
        __builtin_amdgcn_sched_barrier(0);

        // --- MFMA: 4 gate N-tiles over this wave's K quarter ---
        f32x4 acc[4] = {};
        #pragma unroll
        for (int kk = 0; kk < 8; ++kk) {
            bf16x8 a = __builtin_bit_cast(bf16x8, afr[kk]);
            #pragma unroll
            for (int n = 0; n < 4; ++n) {
                const int row = n * 16 + frow;
                int byte = row * 2048 + wv * 512 + kk * 64 + fk8 * 2;
                byte ^= (row & 7) << 4;
                bf16x8 bfrag = *(const bf16x8*)((const char*)wlds + byte);
                acc[n] = __builtin_amdgcn_mfma_f32_16x16x32_bf16(a, bfrag, acc[n], 0, 0, 0);
            }
        }

        // --- cross-wave reduce through LDS ---
        #pragma unroll
        for (int n = 0; n < 4; ++n)
            #pragma unroll
            for (int r = 0; r < 4; ++r)
                gbuf[wv][(lane >> 4) * 4 + r][n * 16 + frow] = acc[n][r];
        __syncthreads();

        WAITVM(0);                         // xg arrived
        __builtin_amdgcn_sched_barrier(0);
        bf16x4 xv = __builtin_bit_cast(bf16x4, xr);
        float P[4];
        #pragma unroll
        for (int g = 0; g < 4; ++g)
            P[g] = gbuf[0][b_el][g * 16 + j_el] + gbuf[1][b_el][g * 16 + j_el]
                 + gbuf[2][b_el][g * 16 + j_el] + gbuf[3][b_el][g * 16 + j_el]
                 + (float)xv[g];
        const float ig = fsigmoid(P[0]);
        const float fg = fsigmoid(P[1]);
        const float gg = ftanh_(P[2]);
        const float og = fsigmoid(P[3]);
        c = fg * c + ig * gg;
        const float hv = og * ftanh_(c);

        out[(size_t)(step * BATCH + bg * 16 + b_el) * HID + 16 * hg + j_el] = hv;
        const bf16 hb16 = (bf16)hv;
        store2_cc(hbuf + ((step & 1) ^ 1) * (BATCH * HID)
                       + (size_t)(bg * 16 + b_el) * HID + 16 * hg + j_el,
                  (u32)__builtin_bit_cast(unsigned short, hb16));

        // --- barrier among the 64 WGs of this batch-group ---
        WAITVM(0);                         // h stores acked at LLC
        __syncthreads();                   // ...by ALL waves of this WG
        if (tid == 0)
            __hip_atomic_store(myflag, (u32)(step + 1),
                               __ATOMIC_RELAXED, __HIP_MEMORY_SCOPE_AGENT);
        while (__hip_atomic_load(pollflag, __ATOMIC_RELAXED,
                                 __HIP_MEMORY_SCOPE_AGENT) < (u32)(step + 1))
            __builtin_amdgcn_s_sleep(1);
        asm volatile("" ::: "memory");
        __syncthreads();
    }
}

// ---------------------------------------------------------------------------
extern "C" void kernel_launch(void* const* d_in, const int* in_sizes, int n_in,
                              void* d_out, int out_size, void* d_ws, size_t ws_size,
                              hipStream_t stream) {
    const float* x   = (const float*)d_in[0];   // [512,64,1024]
    const float* wih = (const float*)d_in[1];   // [4096,1024]
    const float* whh = (const float*)d_in[2];   // [4096,1024]
    const float* bih = (const float*)d_in[3];   // [4096]
    const float* bhh = (const float*)d_in[4];   // [4096]
    float* out = (float*)d_out;                 // [512,64,1024]

    char* ws = (char*)d_ws;
    size_t off = 0;
    bf16* xgp  = (bf16*)(ws + off); off += (size_t)MROWS * NG * 2;      // 256 MB
    bf16* xb   = (bf16*)(ws + off); off += (size_t)MROWS * DIM * 2;     //  64 MB
    bf16* wihp = (bf16*)(ws + off); off += (size_t)NG * DIM * 2;        //   8 MB
    float* bsum = (float*)(ws + off); off += (size_t)NG * 4;            //  16 KB
    bf16* hbuf = (bf16*)(ws + off); off += (size_t)2 * BATCH * HID * 2; // 256 KB
    u32* flags = (u32*)(ws + off); off += 256 * 16 * 4;                 //  16 KB
    (void)ws_size; (void)in_sizes; (void)n_in; (void)out_size;

    prep_kernel<<<2048, 256, 0, stream>>>(x, wih, bih, bhh,
                                          xb, wihp, bsum, hbuf, flags);
    gemm_kernel<<<8192, 256, 0, stream>>>(xb, wihp, bsum, xgp);
    lstm_kernel<<<256, 256, 0, stream>>>(xgp, whh, hbuf, flags, out);
}